// Round 3
// baseline (158.555 us; speedup 1.0000x reference)
//
#include <hip/hip_runtime.h>
#include <math.h>

// ANModel forward, round 3: two-kernel split for parallelism.
// Structural reductions (verified exact in R1/R2, absmax 0.0):
//  - loop iteration i=0 is dead; only i=1 params matter
//  - only 6 rows of x_adapt per batch are consumed
//  - emb linearity folds the edge path
// New in R3:
//  - wx = (sum_j w_j * obs_all_j) @ w_obs + deg*b_obs  -> no per-node x precompute
//  - agdot + deg*be3 = (agge @ we1 + deg*be1) @ W3     -> no we3 precompute
//  - K1: 48 blocks, one per (batch, m) selected row; K2: 8 blocks, MLP head.

constexpr int Bc   = 8;
constexpr int Nc   = 512;
constexpr int Mc   = 6;
constexpr int EDc  = 8;
constexpr int SRCc = 64;
constexpr int OBSc = 32;
constexpr int Dc   = 16;
constexpr int Hc   = 64;

// ---------------- Kernel 1: per-(b,m) selected-row GNN computation ----------
__global__ __launch_bounds__(256) void an_rows_kernel(
    const float* __restrict__ obs_all,    // (B,512,32)
    const float* __restrict__ edge_attrs, // (B,512,512,8)
    const int*   __restrict__ ridxs,      // (B,)
    const int*   __restrict__ rni,        // (512,6)
    const int*   __restrict__ rnm,        // (512,6)
    const float* __restrict__ A,          // (512,512)
    const float* __restrict__ PA,         // (512,512)
    const float* __restrict__ w_obs,      // (32,16)
    const float* __restrict__ b_obs,      // (16,)
    const float* __restrict__ res_w,      // (2,16,16)
    const float* __restrict__ res_b,      // (2,16)
    const float* __restrict__ ge_we,      // (2,8,16)
    const float* __restrict__ ge_be,      // (2,16)
    const float* __restrict__ ge_wemb,    // (2,48,16)
    const float* __restrict__ ge_bemb,    // (2,16)
    float* __restrict__ sel_out)          // (B,6,16) in d_ws
{
    const int blk = blockIdx.x;           // 0..47
    const int b   = blk / Mc;
    const int m   = blk % Mc;
    const int tid = threadIdx.x;

    __shared__ float s_w[Nc];             // (A+PA)[i,:]
    __shared__ float s_woa[8][OBSc];      // partial sum_j w_j * obs_all_j
    __shared__ float s_ag[32][EDc];       // partial sum_j w_j * E[i,j,:]
    __shared__ float s_oai[OBSc];         // obs_all[b,i,:]
    __shared__ float s_woaf[OBSc];
    __shared__ float s_agf[EDc];
    __shared__ float s_xi[Dc];
    __shared__ float s_wx[Dc];
    __shared__ float s_q[Dc];
    __shared__ float s_deg;
    __shared__ int   s_i, s_mk;

    if (tid == 0) {
        const int r = ridxs[b];
        s_i  = rni[r * Mc + m];
        s_mk = rnm[r * Mc + m];
    }
    __syncthreads();
    const int i = s_i;

    // stage w row (coalesced), and obs_all row i
    for (int t = tid; t < Nc; t += 256)
        s_w[t] = A[(size_t)i * Nc + t] + PA[(size_t)i * Nc + t];
    if (tid < OBSc)
        s_oai[tid] = obs_all[((size_t)b * Nc + i) * OBSc + tid];
    __syncthreads();

    // woa partials: 8 j-groups x 32 dims (coalesced: consecutive d per group)
    {
        const int d = tid & 31, jg = tid >> 5;
        const float* __restrict__ oab = obs_all + (size_t)b * Nc * OBSc;
        float acc = 0.f;
        #pragma unroll 4
        for (int t = 0; t < Nc / 8; ++t) {
            const int j = t * 8 + jg;
            acc = fmaf(s_w[j], oab[(size_t)j * OBSc + d], acc);
        }
        s_woa[jg][d] = acc;
    }
    // agge partials: 32 j-groups x 8 dims (wave reads 64 consecutive floats)
    {
        const int e = tid & 7, jg = tid >> 3;
        const float* __restrict__ Erow = edge_attrs + ((size_t)b * Nc + i) * Nc * EDc;
        float acc = 0.f;
        #pragma unroll 4
        for (int t = 0; t < Nc / 32; ++t) {
            const int j = t * 32 + jg;
            acc = fmaf(s_w[j], Erow[(size_t)j * EDc + e], acc);
        }
        s_ag[jg][e] = acc;
    }
    // deg on wave 0
    if (tid < 64) {
        float dv = 0.f;
        #pragma unroll
        for (int t = 0; t < Nc / 64; ++t) dv += s_w[t * 64 + tid];
        #pragma unroll
        for (int s = 1; s < 64; s <<= 1) dv += __shfl_xor(dv, s);
        if (tid == 0) s_deg = dv;
    }
    __syncthreads();

    const float deg = s_deg;
    if (tid < OBSc) {
        float acc = 0.f;
        #pragma unroll
        for (int g = 0; g < 8; ++g) acc += s_woa[g][tid];
        s_woaf[tid] = acc;
    } else if (tid >= 64 && tid < 64 + EDc) {
        const int e = tid - 64;
        float acc = 0.f;
        #pragma unroll
        for (int g = 0; g < 32; ++g) acc += s_ag[g][e];
        s_agf[e] = acc;
    } else if (tid >= 128 && tid < 128 + Dc) {
        // x_i = obs_all[b,i] @ w_obs + b_obs
        const int d = tid - 128;
        float acc = b_obs[d];
        #pragma unroll 8
        for (int k = 0; k < OBSc; ++k) acc = fmaf(s_oai[k], w_obs[k * Dc + d], acc);
        s_xi[d] = acc;
    }
    __syncthreads();

    if (tid < Dc) {
        // wx = woaf @ w_obs + deg * b_obs
        const int d = tid;
        float acc = deg * b_obs[d];
        #pragma unroll 8
        for (int k = 0; k < OBSc; ++k) acc = fmaf(s_woaf[k], w_obs[k * Dc + d], acc);
        s_wx[d] = acc;
    } else if (tid >= 64 && tid < 64 + Dc) {
        // q = agf @ we1 + deg * be1
        const int d = tid - 64;
        float acc = deg * ge_be[Dc + d];
        #pragma unroll
        for (int e = 0; e < EDc; ++e)
            acc = fmaf(s_agf[e], ge_we[EDc * Dc + e * Dc + d], acc);
        s_q[d] = acc;
    }
    __syncthreads();

    if (tid < Dc) {
        const int d = tid;
        const float* __restrict__ wemb1 = ge_wemb + 3 * Dc * Dc; // W1|W2|W3 rows
        float resv = res_b[Dc + d];
        float acc  = deg * ge_bemb[Dc + d];
        #pragma unroll
        for (int k = 0; k < Dc; ++k) {
            resv = fmaf(s_xi[k], res_w[Dc * Dc + k * Dc + d], resv);
            acc  = fmaf(deg * s_xi[k], wemb1[k * Dc + d], acc);           // @W1 * deg
            acc  = fmaf(s_wx[k],       wemb1[(Dc + k) * Dc + d], acc);    // adj@(x@W2)
            acc  = fmaf(s_q[k],        wemb1[(2 * Dc + k) * Dc + d], acc);// edge @W3
        }
        float xa = resv + acc;
        xa = xa > 0.f ? xa : 0.f;
        sel_out[((size_t)b * Mc + m) * Dc + d] = (s_mk == 0) ? -1.0f : xa;
    }
}

// ---------------- Kernel 2: gated MLP head ---------------------------------
__global__ __launch_bounds__(128) void an_head_kernel(
    const float* __restrict__ obs,        // (B,64)
    const float* __restrict__ w_src,      // (64,96)
    const float* __restrict__ b_src,      // (96,)
    const float* __restrict__ gated_w,    // (192,32)
    const float* __restrict__ gated_b,    // (32,)
    const float* __restrict__ base_w1,    // (16,64)
    const float* __restrict__ base_b1,    // (64,)
    const float* __restrict__ base_w2,    // (64,64)
    const float* __restrict__ base_b2,    // (64,)
    const float* __restrict__ act_w,      // (64,6)
    const float* __restrict__ act_b,      // (6,)
    const float* __restrict__ sel_in,     // (B,96) in d_ws
    float* __restrict__ out)              // (B,6)
{
    const int b   = blockIdx.x;
    const int tid = threadIdx.x;
    __shared__ float s_sel[96], s_obsp[96], s_g[32], s_h0[Dc], s_h1[Hc], s_h2[Hc];

    if (tid < 96) {
        s_sel[tid] = sel_in[b * 96 + tid];
        float acc = b_src[tid];
        #pragma unroll 8
        for (int s = 0; s < SRCc; ++s)
            acc = fmaf(obs[b * SRCc + s], w_src[s * 96 + tid], acc);
        s_obsp[tid] = acc;
    }
    __syncthreads();
    if (tid < 32) {
        float gv = gated_b[tid];
        for (int t = 0; t < 96; ++t) gv = fmaf(s_obsp[t], gated_w[t * 32 + tid], gv);
        for (int t = 0; t < 96; ++t) gv = fmaf(s_sel[t],  gated_w[(96 + t) * 32 + tid], gv);
        s_g[tid] = gv;
    }
    __syncthreads();
    if (tid < Dc)
        s_h0[tid] = s_g[tid] * (1.0f / (1.0f + expf(-s_g[tid + Dc])));
    __syncthreads();
    if (tid < Hc) {
        float acc = base_b1[tid];
        #pragma unroll
        for (int k = 0; k < Dc; ++k) acc = fmaf(s_h0[k], base_w1[k * Hc + tid], acc);
        s_h1[tid] = acc > 0.f ? acc : 0.f;
    }
    __syncthreads();
    if (tid < Hc) {
        float acc = base_b2[tid];
        #pragma unroll 8
        for (int k = 0; k < Hc; ++k) acc = fmaf(s_h1[k], base_w2[k * Hc + tid], acc);
        s_h2[tid] = acc > 0.f ? acc : 0.f;
    }
    __syncthreads();
    if (tid < Mc) {
        float acc = act_b[tid];
        #pragma unroll 8
        for (int k = 0; k < Hc; ++k) acc = fmaf(s_h2[k], act_w[k * Mc + tid], acc);
        out[b * Mc + tid] = acc;
    }
}

extern "C" void kernel_launch(void* const* d_in, const int* in_sizes, int n_in,
                              void* d_out, int out_size, void* d_ws, size_t ws_size,
                              hipStream_t stream) {
    (void)in_sizes; (void)n_in; (void)ws_size; (void)out_size;
    float* sel_ws = (float*)d_ws;   // 48*16 floats

    an_rows_kernel<<<dim3(Bc * Mc), dim3(256), 0, stream>>>(
        (const float*)d_in[1],  (const float*)d_in[2],  (const int*)d_in[3],
        (const int*)  d_in[4],  (const int*)  d_in[5],
        (const float*)d_in[6],  (const float*)d_in[7],
        (const float*)d_in[10], (const float*)d_in[11],
        (const float*)d_in[12], (const float*)d_in[13],
        (const float*)d_in[14], (const float*)d_in[15],
        (const float*)d_in[16], (const float*)d_in[17],
        sel_ws);

    an_head_kernel<<<dim3(Bc), dim3(128), 0, stream>>>(
        (const float*)d_in[0],  (const float*)d_in[8],  (const float*)d_in[9],
        (const float*)d_in[18], (const float*)d_in[19],
        (const float*)d_in[20], (const float*)d_in[21],
        (const float*)d_in[22], (const float*)d_in[23],
        (const float*)d_in[24], (const float*)d_in[25],
        sel_ws, (float*)d_out);
}